// Round 1
// baseline (99.879 us; speedup 1.0000x reference)
//
#include <hip/hip_runtime.h>
#include <hip/hip_bf16.h>

#define NUM_BINS 512
#define T_LEN 256
#define B_LEN 16
#define WIN 101
#define HALF 50
#define NOUT 128

// ---------------- Kernel 1: per-frame 512-bin histogram + L2 normalize -------
// grid = 4096 blocks (one per frame), block = 256 threads.
// frames: int32 RGB interleaved; frame = 4096 pixels = 12288 ints = 3072 int4.
// Thread t owns int4 indices [t*12, t*12+12) = pixels [t*16, t*16+16)
// (192 contiguous bytes per thread; every fetched byte used exactly once).
__global__ __launch_bounds__(256) void hist_kernel(const int* __restrict__ frames,
                                                   float* __restrict__ xout) {
    __shared__ int hist[NUM_BINS];
    __shared__ float red[4];
    const int f = blockIdx.x;
    const int tid = threadIdx.x;

    hist[tid] = 0;
    hist[tid + 256] = 0;
    __syncthreads();

    const int4* base = (const int4*)(frames + (size_t)f * 12288);
    #pragma unroll
    for (int g = 0; g < 4; ++g) {
        int4 a = base[tid * 12 + g * 3 + 0];
        int4 b = base[tid * 12 + g * 3 + 1];
        int4 c = base[tid * 12 + g * 3 + 2];
        // pixels: (a.x,a.y,a.z) (a.w,b.x,b.y) (b.z,b.w,c.x) (c.y,c.z,c.w)
        atomicAdd(&hist[((a.x >> 5) << 6) | ((a.y >> 5) << 3) | (a.z >> 5)], 1);
        atomicAdd(&hist[((a.w >> 5) << 6) | ((b.x >> 5) << 3) | (b.y >> 5)], 1);
        atomicAdd(&hist[((b.z >> 5) << 6) | ((b.w >> 5) << 3) | (c.x >> 5)], 1);
        atomicAdd(&hist[((c.y >> 5) << 6) | ((c.z >> 5) << 3) | (c.w >> 5)], 1);
    }
    __syncthreads();

    const int h0 = hist[tid];
    const int h1 = hist[tid + 256];
    float ss = (float)h0 * (float)h0 + (float)h1 * (float)h1;
    #pragma unroll
    for (int off = 32; off; off >>= 1) ss += __shfl_down(ss, off, 64);
    const int lane = tid & 63;
    const int wave = tid >> 6;
    if (lane == 0) red[wave] = ss;
    __syncthreads();
    const float tot = red[0] + red[1] + red[2] + red[3];
    // tot >= 4096^2/512 = 32768 always (4096 pixels), no epsilon needed
    const float inv = 1.0f / sqrtf(tot);
    float* xrow = xout + (size_t)f * NUM_BINS;
    xrow[tid] = (float)h0 * inv;
    xrow[tid + 256] = (float)h1 * inv;
}

// ---------------- Kernel 2: windowed similarity + FC + ReLU ------------------
// grid = (T=256, B=16), block = 256 threads (4 waves).
// Per block: stage x[b,t] (512 f32) in LDS; waves compute the 101 dots
// windowed[w] = dot(x[b,t], x[b,t+w-50]); then threads 0..127 do the FC.
__global__ __launch_bounds__(256) void winfc_kernel(const float* __restrict__ x,
                                                    const float* __restrict__ fc_w,
                                                    const float* __restrict__ fc_b,
                                                    float* __restrict__ out) {
    __shared__ float xt[NUM_BINS];
    __shared__ float win[WIN];
    const int t = blockIdx.x;
    const int b = blockIdx.y;
    const int tid = threadIdx.x;
    const int lane = tid & 63;
    const int wave = tid >> 6;

    const float* xb = x + ((size_t)b * T_LEN) * NUM_BINS;
    // load x[b,t] into LDS (2 floats per thread)
    xt[tid] = xb[(size_t)t * NUM_BINS + tid];
    xt[tid + 256] = xb[(size_t)t * NUM_BINS + tid + 256];
    __syncthreads();

    const float4* xt4 = (const float4*)xt;  // 128 float4
    for (int w = wave; w < WIN; w += 4) {
        const int s = t + w - HALF;
        float acc = 0.0f;
        if (s >= 0 && s < T_LEN) {
            const float4* xs4 = (const float4*)(xb + (size_t)s * NUM_BINS);
            float4 p0 = xt4[lane];
            float4 q0 = xs4[lane];
            float4 p1 = xt4[lane + 64];
            float4 q1 = xs4[lane + 64];
            acc = p0.x * q0.x + p0.y * q0.y + p0.z * q0.z + p0.w * q0.w
                + p1.x * q1.x + p1.y * q1.y + p1.z * q1.z + p1.w * q1.w;
            #pragma unroll
            for (int off = 32; off; off >>= 1) acc += __shfl_down(acc, off, 64);
        }
        if (lane == 0) win[w] = acc;
    }
    __syncthreads();

    if (tid < NOUT) {
        const float* wrow = fc_w + tid * WIN;
        float acc = fc_b[tid];
        #pragma unroll
        for (int w = 0; w < WIN; ++w) acc += win[w] * wrow[w];
        out[((size_t)(b * T_LEN + t)) * NOUT + tid] = fmaxf(acc, 0.0f);
    }
}

extern "C" void kernel_launch(void* const* d_in, const int* in_sizes, int n_in,
                              void* d_out, int out_size, void* d_ws, size_t ws_size,
                              hipStream_t stream) {
    const int* frames = (const int*)d_in[0];
    const float* fc_w = (const float*)d_in[1];
    const float* fc_b = (const float*)d_in[2];
    float* out = (float*)d_out;
    float* x = (float*)d_ws;  // 4096 * 512 floats = 8 MB

    hist_kernel<<<B_LEN * T_LEN, 256, 0, stream>>>(frames, x);
    winfc_kernel<<<dim3(T_LEN, B_LEN), 256, 0, stream>>>(x, fc_w, fc_b, out);
}

// Round 2
// 84.496 us; speedup vs baseline: 1.1820x; 1.1820x over previous
//
#include <hip/hip_runtime.h>
#include <hip/hip_bf16.h>

#define NUM_BINS 512
#define T_LEN 256
#define B_LEN 16
#define WIN 101
#define HALF 50
#define NOUT 128

__device__ __forceinline__ float blo(unsigned u) { return __uint_as_float(u << 16); }
__device__ __forceinline__ float bhi(unsigned u) { return __uint_as_float(u & 0xffff0000u); }

// ---------------- Kernel 1: per-frame 512-bin histogram + L2 normalize -------
// grid = 4096 blocks (one per frame), block = 256 threads.
// frames: int32 RGB interleaved; frame = 4096 pixels = 12288 ints = 3072 int4.
// Thread t owns int4 indices [t*12, t*12+12) = pixels [t*16, t*16+16).
// Output: bf16 rows (f32 normalization math, bf16 store).
__global__ __launch_bounds__(256) void hist_kernel(const int* __restrict__ frames,
                                                   __hip_bfloat16* __restrict__ xout) {
    __shared__ int hist[NUM_BINS];
    __shared__ float red[4];
    const int f = blockIdx.x;
    const int tid = threadIdx.x;

    hist[tid] = 0;
    hist[tid + 256] = 0;
    __syncthreads();

    const int4* base = (const int4*)(frames + (size_t)f * 12288);
    #pragma unroll
    for (int g = 0; g < 4; ++g) {
        int4 a = base[tid * 12 + g * 3 + 0];
        int4 b = base[tid * 12 + g * 3 + 1];
        int4 c = base[tid * 12 + g * 3 + 2];
        atomicAdd(&hist[((a.x >> 5) << 6) | ((a.y >> 5) << 3) | (a.z >> 5)], 1);
        atomicAdd(&hist[((a.w >> 5) << 6) | ((b.x >> 5) << 3) | (b.y >> 5)], 1);
        atomicAdd(&hist[((b.z >> 5) << 6) | ((b.w >> 5) << 3) | (c.x >> 5)], 1);
        atomicAdd(&hist[((c.y >> 5) << 6) | ((c.z >> 5) << 3) | (c.w >> 5)], 1);
    }
    __syncthreads();

    const int h0 = hist[tid];
    const int h1 = hist[tid + 256];
    float ss = (float)h0 * (float)h0 + (float)h1 * (float)h1;
    #pragma unroll
    for (int off = 32; off; off >>= 1) ss += __shfl_down(ss, off, 64);
    const int lane = tid & 63;
    const int wave = tid >> 6;
    if (lane == 0) red[wave] = ss;
    __syncthreads();
    const float tot = red[0] + red[1] + red[2] + red[3];
    const float inv = 1.0f / sqrtf(tot);
    __hip_bfloat16* xrow = xout + (size_t)f * NUM_BINS;
    xrow[tid] = __float2bfloat16((float)h0 * inv);
    xrow[tid + 256] = __float2bfloat16((float)h1 * inv);
}

// ---------------- Kernel 2: windowed similarity + FC + ReLU ------------------
// 1-D grid of 4096 blocks; b = bid & 15 so XCD (bid % 8) serves only batches
// {xcd, xcd+8}: per-XCD working set = 2 * 256KB bf16 x + 52KB fc_w -> L2-hot.
// Each lane keeps its 8-elem f32 slice of x[b,t] in registers across all 101
// dots; per dot: one 16B bf16 load of the neighbor row slice + 8 FMA + reduce.
__global__ __launch_bounds__(256) void winfc_kernel(const unsigned short* __restrict__ x,
                                                    const float* __restrict__ fc_w,
                                                    const float* __restrict__ fc_b,
                                                    float* __restrict__ out) {
    __shared__ float win[WIN];
    const int bid = blockIdx.x;
    const int b = bid & 15;
    const int t = bid >> 4;
    const int tid = threadIdx.x;
    const int lane = tid & 63;
    const int wave = tid >> 6;

    const unsigned short* xb = x + ((size_t)b * T_LEN) * NUM_BINS;
    const uint4* xt4 = (const uint4*)(xb + (size_t)t * NUM_BINS);
    uint4 p = xt4[lane];
    float xr[8];
    xr[0] = blo(p.x); xr[1] = bhi(p.x);
    xr[2] = blo(p.y); xr[3] = bhi(p.y);
    xr[4] = blo(p.z); xr[5] = bhi(p.z);
    xr[6] = blo(p.w); xr[7] = bhi(p.w);

    for (int w = wave; w < WIN; w += 4) {
        const int s = t + w - HALF;
        float acc = 0.0f;
        if (s >= 0 && s < T_LEN) {
            const uint4* xs4 = (const uint4*)(xb + (size_t)s * NUM_BINS);
            uint4 q = xs4[lane];
            acc = xr[0] * blo(q.x) + xr[1] * bhi(q.x)
                + xr[2] * blo(q.y) + xr[3] * bhi(q.y)
                + xr[4] * blo(q.z) + xr[5] * bhi(q.z)
                + xr[6] * blo(q.w) + xr[7] * bhi(q.w);
            #pragma unroll
            for (int off = 32; off; off >>= 1) acc += __shfl_down(acc, off, 64);
        }
        if (lane == 0) win[w] = acc;
    }
    __syncthreads();

    if (tid < NOUT) {
        const float* wrow = fc_w + tid * WIN;
        float acc = fc_b[tid];
        #pragma unroll
        for (int w = 0; w < WIN; ++w) acc += win[w] * wrow[w];
        out[((size_t)(b * T_LEN + t)) * NOUT + tid] = fmaxf(acc, 0.0f);
    }
}

extern "C" void kernel_launch(void* const* d_in, const int* in_sizes, int n_in,
                              void* d_out, int out_size, void* d_ws, size_t ws_size,
                              hipStream_t stream) {
    const int* frames = (const int*)d_in[0];
    const float* fc_w = (const float*)d_in[1];
    const float* fc_b = (const float*)d_in[2];
    float* out = (float*)d_out;
    __hip_bfloat16* x = (__hip_bfloat16*)d_ws;  // 4096 * 512 bf16 = 4 MB

    hist_kernel<<<B_LEN * T_LEN, 256, 0, stream>>>(frames, x);
    winfc_kernel<<<B_LEN * T_LEN, 256, 0, stream>>>((const unsigned short*)x, fc_w, fc_b, out);
}

// Round 3
// 53.691 us; speedup vs baseline: 1.8602x; 1.5737x over previous
//
#include <hip/hip_runtime.h>
#include <hip/hip_bf16.h>

#define NUM_BINS 512
#define T_LEN 256
#define B_LEN 16
#define WIN 101
#define HALF 50
#define NOUT 128

typedef __attribute__((ext_vector_type(8))) short short8;
typedef __attribute__((ext_vector_type(4))) float f32x4;

__device__ __forceinline__ unsigned short f2bf(float f) {
    unsigned u = __float_as_uint(f);
    u += 0x7fff + ((u >> 16) & 1);   // round-to-nearest-even
    return (unsigned short)(u >> 16);
}

// ---------------- Kernel 1: per-frame 512-bin histogram + L2 normalize -------
// grid = 4096 blocks (one per frame), block = 256 threads. HBM-bound (201 MB).
__global__ __launch_bounds__(256) void hist_kernel(const int* __restrict__ frames,
                                                   __hip_bfloat16* __restrict__ xout) {
    __shared__ int hist[NUM_BINS];
    __shared__ float red[4];
    const int f = blockIdx.x;
    const int tid = threadIdx.x;

    hist[tid] = 0;
    hist[tid + 256] = 0;
    __syncthreads();

    const int4* base = (const int4*)(frames + (size_t)f * 12288);
    #pragma unroll
    for (int g = 0; g < 4; ++g) {
        int4 a = base[tid * 12 + g * 3 + 0];
        int4 b = base[tid * 12 + g * 3 + 1];
        int4 c = base[tid * 12 + g * 3 + 2];
        atomicAdd(&hist[((a.x >> 5) << 6) | ((a.y >> 5) << 3) | (a.z >> 5)], 1);
        atomicAdd(&hist[((a.w >> 5) << 6) | ((b.x >> 5) << 3) | (b.y >> 5)], 1);
        atomicAdd(&hist[((b.z >> 5) << 6) | ((b.w >> 5) << 3) | (c.x >> 5)], 1);
        atomicAdd(&hist[((c.y >> 5) << 6) | ((c.z >> 5) << 3) | (c.w >> 5)], 1);
    }
    __syncthreads();

    const int h0 = hist[tid];
    const int h1 = hist[tid + 256];
    float ss = (float)h0 * (float)h0 + (float)h1 * (float)h1;
    #pragma unroll
    for (int off = 32; off; off >>= 1) ss += __shfl_down(ss, off, 64);
    const int lane = tid & 63;
    const int wave = tid >> 6;
    if (lane == 0) red[wave] = ss;
    __syncthreads();
    const float tot = red[0] + red[1] + red[2] + red[3];
    const float inv = 1.0f / sqrtf(tot);
    __hip_bfloat16* xrow = xout + (size_t)f * NUM_BINS;
    xrow[tid] = __float2bfloat16((float)h0 * inv);
    xrow[tid + 256] = __float2bfloat16((float)h1 * inv);
}

// ---------------- Kernel 2: MFMA banded sim + window extract + MFMA FC -------
// grid = 256 blocks (bid = tt*16 + b so XCD = b%8 -> per-XCD x slice L2-hot).
// Block = (b, 16 t-rows). Phase 1: sim[16][128] band via mfma 16x16x32 bf16,
// A/B fragments loaded straight from L2-resident x (B^T layout: both operands
// are K-contiguous 16B/lane). Phase 2: diagonal extract -> bf16 win[16][128]
// (w>=101 zero-padded). Phase 3: FC via mfma (K=128), bias+relu, store.
__global__ __launch_bounds__(256) void simfc_kernel(const unsigned short* __restrict__ x,
                                                    const float* __restrict__ fc_w,
                                                    const float* __restrict__ fc_b,
                                                    float* __restrict__ out) {
    __shared__ float sim_lds[16 * 132];          // stride 132: 2-way banks on C-store
    __shared__ unsigned short win_lds[16 * 136]; // stride 136: 2-way banks on A-read

    const int bid = blockIdx.x;
    const int b = bid & 15;
    const int tt = bid >> 4;
    const int t0 = tt * 16;
    const int tid = threadIdx.x;
    const int lane = tid & 63;
    const int wave = tid >> 6;
    const int l15 = lane & 15;
    const int kg = lane >> 4;    // k-chunk 0..3

    const unsigned short* xb = x + (size_t)b * T_LEN * NUM_BINS;

    // ---- Phase 1: banded sim. Wave w owns s-tiles j = 2w, 2w+1.
    f32x4 acc0 = {0.f, 0.f, 0.f, 0.f};
    f32x4 acc1 = {0.f, 0.f, 0.f, 0.f};
    const short8 zero8 = {0, 0, 0, 0, 0, 0, 0, 0};
    {
        const int rowA = t0 + l15;
        const int s0 = t0 - HALF + 32 * wave;
        const int rb0 = s0 + l15;
        const int rb1 = s0 + 16 + l15;
        const bool v0 = (rb0 >= 0) && (rb0 < T_LEN);
        const bool v1 = (rb1 >= 0) && (rb1 < T_LEN);
        const int rc0 = min(max(rb0, 0), T_LEN - 1);
        const int rc1 = min(max(rb1, 0), T_LEN - 1);
        const unsigned short* pa = xb + (size_t)rowA * NUM_BINS + kg * 8;
        const unsigned short* p0 = xb + (size_t)rc0 * NUM_BINS + kg * 8;
        const unsigned short* p1 = xb + (size_t)rc1 * NUM_BINS + kg * 8;
        #pragma unroll
        for (int ks = 0; ks < 16; ++ks) {
            short8 a  = *(const short8*)(pa + ks * 32);
            short8 b0 = *(const short8*)(p0 + ks * 32);
            short8 b1 = *(const short8*)(p1 + ks * 32);
            b0 = v0 ? b0 : zero8;
            b1 = v1 ? b1 : zero8;
            acc0 = __builtin_amdgcn_mfma_f32_16x16x32_bf16(a, b0, acc0, 0, 0, 0);
            acc1 = __builtin_amdgcn_mfma_f32_16x16x32_bf16(a, b1, acc1, 0, 0, 0);
        }
        // C layout: col = lane&15, row = (lane>>4)*4 + r
        const int j0 = 2 * wave;
        #pragma unroll
        for (int r = 0; r < 4; ++r) {
            const int row = kg * 4 + r;
            sim_lds[row * 132 + j0 * 16 + l15] = acc0[r];
            sim_lds[row * 132 + (j0 + 1) * 16 + l15] = acc1[r];
        }
    }
    __syncthreads();

    // ---- Phase 2: windowed[i][w] = sim[i][i+w], bf16, zero-pad w>=101.
    {
        const int i = tid >> 4;
        const int w8 = (tid & 15) * 8;
        short8 v;
        #pragma unroll
        for (int e = 0; e < 8; ++e) {
            const int w = w8 + e;
            const float f = (w < WIN) ? sim_lds[i * 132 + i + w] : 0.0f;
            v[e] = (short)f2bf(f);
        }
        *(short8*)(&win_lds[i * 136 + w8]) = v;
    }
    __syncthreads();

    // ---- Phase 3: out = relu(win @ fc_w^T + b) via MFMA, K=128.
    // B fragment lane: col o = n0 + (lane&15), k-chunk w = ks*32 + kg*8,
    // elements fc_w[o][w..w+7] (row-major contiguous), cvt f32->bf16 inline.
    {
        f32x4 o0 = {0.f, 0.f, 0.f, 0.f};
        f32x4 o1 = {0.f, 0.f, 0.f, 0.f};
        const int n0 = wave * 32;
        const int oA = n0 + l15;
        const int oB = n0 + 16 + l15;
        const float* pwA = fc_w + oA * WIN;
        const float* pwB = fc_w + oB * WIN;
        #pragma unroll
        for (int ks = 0; ks < 4; ++ks) {
            const int wbase = ks * 32 + kg * 8;
            short8 a = *(const short8*)(&win_lds[l15 * 136 + wbase]);
            short8 b0, b1;
            #pragma unroll
            for (int e = 0; e < 8; ++e) {
                const int w = wbase + e;
                const int wc = min(w, WIN - 1);
                float vA = pwA[wc];
                float vB = pwB[wc];
                b0[e] = (short)((w < WIN) ? f2bf(vA) : (unsigned short)0);
                b1[e] = (short)((w < WIN) ? f2bf(vB) : (unsigned short)0);
            }
            o0 = __builtin_amdgcn_mfma_f32_16x16x32_bf16(a, b0, o0, 0, 0, 0);
            o1 = __builtin_amdgcn_mfma_f32_16x16x32_bf16(a, b1, o1, 0, 0, 0);
        }
        const float biasA = fc_b[oA];
        const float biasB = fc_b[oB];
        float* ob = out + ((size_t)b * T_LEN + t0) * NOUT;
        #pragma unroll
        for (int r = 0; r < 4; ++r) {
            const int row = kg * 4 + r;
            ob[row * NOUT + oA] = fmaxf(o0[r] + biasA, 0.0f);
            ob[row * NOUT + oB] = fmaxf(o1[r] + biasB, 0.0f);
        }
    }
}

extern "C" void kernel_launch(void* const* d_in, const int* in_sizes, int n_in,
                              void* d_out, int out_size, void* d_ws, size_t ws_size,
                              hipStream_t stream) {
    const int* frames = (const int*)d_in[0];
    const float* fc_w = (const float*)d_in[1];
    const float* fc_b = (const float*)d_in[2];
    float* out = (float*)d_out;
    __hip_bfloat16* x = (__hip_bfloat16*)d_ws;  // 4096 * 512 bf16 = 4 MB

    hist_kernel<<<B_LEN * T_LEN, 256, 0, stream>>>(frames, x);
    simfc_kernel<<<B_LEN * T_LEN / 16, 256, 0, stream>>>((const unsigned short*)x, fc_w, fc_b, out);
}

// Round 4
// 44.856 us; speedup vs baseline: 2.2267x; 1.1970x over previous
//
#include <hip/hip_runtime.h>
#include <hip/hip_bf16.h>

#define NUM_BINS 512
#define T_LEN 256
#define B_LEN 16
#define WIN 101
#define HALF 50
#define NOUT 128

typedef __attribute__((ext_vector_type(8))) short short8;
typedef __attribute__((ext_vector_type(4))) float f32x4;

__device__ __forceinline__ unsigned short f2bf(float f) {
    unsigned u = __float_as_uint(f);
    u += 0x7fff + ((u >> 16) & 1);   // round-to-nearest-even
    return (unsigned short)(u >> 16);
}

// ---------------- Kernel 1: per-frame 512-bin histogram + L2 normalize -------
// grid = 4096 blocks (one per frame), block = 256 threads. HBM-bound (201 MB).
// Pixel-major interleave: iteration i loads pixels [i*256 .. i*256+255] across
// the block as int3 (dwordx3) at 12B lane stride -> each instruction covers a
// contiguous 768B/wave span; every fetched 64B line fully consumed (no L1
// thrash / L2 amplification, unlike 192B-stride per-thread ownership).
__global__ __launch_bounds__(256) void hist_kernel(const int* __restrict__ frames,
                                                   __hip_bfloat16* __restrict__ xout) {
    __shared__ int hist[NUM_BINS];
    __shared__ float red[4];
    const int f = blockIdx.x;
    const int tid = threadIdx.x;

    hist[tid] = 0;
    hist[tid + 256] = 0;
    __syncthreads();

    const int* base = frames + (size_t)f * 12288;
    #pragma unroll 4
    for (int i = 0; i < 16; ++i) {
        const int p = i * 256 + tid;
        int3 v = *(const int3*)(base + (size_t)p * 3);
        atomicAdd(&hist[((v.x >> 5) << 6) | ((v.y >> 5) << 3) | (v.z >> 5)], 1);
    }
    __syncthreads();

    const int h0 = hist[tid];
    const int h1 = hist[tid + 256];
    float ss = (float)h0 * (float)h0 + (float)h1 * (float)h1;
    #pragma unroll
    for (int off = 32; off; off >>= 1) ss += __shfl_down(ss, off, 64);
    const int lane = tid & 63;
    const int wave = tid >> 6;
    if (lane == 0) red[wave] = ss;
    __syncthreads();
    const float tot = red[0] + red[1] + red[2] + red[3];
    const float inv = 1.0f / sqrtf(tot);
    __hip_bfloat16* xrow = xout + (size_t)f * NUM_BINS;
    xrow[tid] = __float2bfloat16((float)h0 * inv);
    xrow[tid + 256] = __float2bfloat16((float)h1 * inv);
}

// ---------------- Kernel 2: MFMA banded sim + window extract + MFMA FC -------
// grid = 256 blocks (bid = tt*16 + b -> XCD = b%8 keeps per-XCD x slice hot),
// block = 512 threads (8 waves -> 2 waves/SIMD for latency hiding).
// Phase 1: wave j computes s-tile j of the 16x128 sim band (16 MFMAs, K=512),
// operands loaded straight from L2/L3-resident bf16 x (both K-contiguous).
// Phase 2: diagonal extract win[i][w] = sim[i][i+w] -> bf16, zero-pad w>=101.
// Phase 3: wave j computes 16 FC outputs o = j*16+l15 via MFMA (K=128).
__global__ __launch_bounds__(512) void simfc_kernel(const unsigned short* __restrict__ x,
                                                    const float* __restrict__ fc_w,
                                                    const float* __restrict__ fc_b,
                                                    float* __restrict__ out) {
    __shared__ float sim_lds[16 * 132];
    __shared__ unsigned short win_lds[16 * 136];

    const int bid = blockIdx.x;
    const int b = bid & 15;
    const int tt = bid >> 4;
    const int t0 = tt * 16;
    const int tid = threadIdx.x;
    const int lane = tid & 63;
    const int wave = tid >> 6;   // 0..7
    const int l15 = lane & 15;
    const int kg = lane >> 4;    // k-chunk 0..3

    const unsigned short* xb = x + (size_t)b * T_LEN * NUM_BINS;

    // ---- Phase 1: s-tile `wave`: cols s = t0-50+16*wave .. +15
    {
        f32x4 acc = {0.f, 0.f, 0.f, 0.f};
        const short8 zero8 = {0, 0, 0, 0, 0, 0, 0, 0};
        const int rowA = t0 + l15;
        const int rb = t0 - HALF + 16 * wave + l15;
        const bool vv = (rb >= 0) && (rb < T_LEN);
        const int rc = min(max(rb, 0), T_LEN - 1);
        const unsigned short* pa = xb + (size_t)rowA * NUM_BINS + kg * 8;
        const unsigned short* ps = xb + (size_t)rc * NUM_BINS + kg * 8;
        #pragma unroll
        for (int ks = 0; ks < 16; ++ks) {
            short8 a  = *(const short8*)(pa + ks * 32);
            short8 bb = *(const short8*)(ps + ks * 32);
            bb = vv ? bb : zero8;
            acc = __builtin_amdgcn_mfma_f32_16x16x32_bf16(a, bb, acc, 0, 0, 0);
        }
        // C layout: col = lane&15 (s within tile), row = kg*4 + r (t row)
        #pragma unroll
        for (int r = 0; r < 4; ++r)
            sim_lds[(kg * 4 + r) * 132 + wave * 16 + l15] = acc[r];
    }
    __syncthreads();

    // ---- Phase 2: windowed[i][w] = sim[i][i+w], bf16, zero-pad w>=101.
    if (tid < 256) {
        const int i = tid >> 4;
        const int w8 = (tid & 15) * 8;
        short8 v;
        #pragma unroll
        for (int e = 0; e < 8; ++e) {
            const int w = w8 + e;
            const float fv = (w < WIN) ? sim_lds[i * 132 + i + w] : 0.0f;
            v[e] = (short)f2bf(fv);
        }
        *(short8*)(&win_lds[i * 136 + w8]) = v;
    }
    __syncthreads();

    // ---- Phase 3: wave owns outputs o = wave*16 + l15, K=128 MFMA.
    {
        f32x4 o0 = {0.f, 0.f, 0.f, 0.f};
        const int o = wave * 16 + l15;
        const float* pw = fc_w + o * WIN;
        #pragma unroll
        for (int ks = 0; ks < 4; ++ks) {
            const int wbase = ks * 32 + kg * 8;
            short8 a = *(const short8*)(&win_lds[l15 * 136 + wbase]);
            short8 b0;
            #pragma unroll
            for (int e = 0; e < 8; ++e) {
                const int w = wbase + e;
                b0[e] = (short)((w < WIN) ? f2bf(pw[w]) : (unsigned short)0);
            }
            o0 = __builtin_amdgcn_mfma_f32_16x16x32_bf16(a, b0, o0, 0, 0, 0);
        }
        const float bias = fc_b[o];
        float* ob = out + ((size_t)b * T_LEN + t0) * NOUT;
        #pragma unroll
        for (int r = 0; r < 4; ++r)
            ob[(kg * 4 + r) * NOUT + o] = fmaxf(o0[r] + bias, 0.0f);
    }
}

extern "C" void kernel_launch(void* const* d_in, const int* in_sizes, int n_in,
                              void* d_out, int out_size, void* d_ws, size_t ws_size,
                              hipStream_t stream) {
    const int* frames = (const int*)d_in[0];
    const float* fc_w = (const float*)d_in[1];
    const float* fc_b = (const float*)d_in[2];
    float* out = (float*)d_out;
    __hip_bfloat16* x = (__hip_bfloat16*)d_ws;  // 4096 * 512 bf16 = 4 MB

    hist_kernel<<<B_LEN * T_LEN, 256, 0, stream>>>(frames, x);
    simfc_kernel<<<B_LEN * T_LEN / 16, 512, 0, stream>>>((const unsigned short*)x, fc_w, fc_b, out);
}

// Round 5
// 44.436 us; speedup vs baseline: 2.2477x; 1.0095x over previous
//
#include <hip/hip_runtime.h>
#include <hip/hip_bf16.h>

#define NUM_BINS 512
#define T_LEN 256
#define B_LEN 16
#define WIN 101
#define HALF 50
#define NOUT 128

typedef __attribute__((ext_vector_type(8))) short short8;
typedef __attribute__((ext_vector_type(4))) float f32x4;

__device__ __forceinline__ unsigned short f2bf(float f) {
    unsigned u = __float_as_uint(f);
    u += 0x7fff + ((u >> 16) & 1);   // round-to-nearest-even
    return (unsigned short)(u >> 16);
}

__device__ __forceinline__ int bin3(int3 v) {
    return ((v.x >> 5) << 6) | ((v.y >> 5) << 3) | (v.z >> 5);
}

// ---------------- Kernel 1: histograms (2 frames/block) + fc_w preswizzle ----
// 2048 frame-blocks (2 frames each, dual LDS histograms so frame-1 loads
// overlap frame-0 reduce/write) + 8 tail blocks converting fc_w to a bf16
// MFMA B-fragment layout [og][ks][kg][l15][e] zero-padded to K=128.
__global__ __launch_bounds__(256, 8) void hist_kernel(const int* __restrict__ frames,
                                                      const float* __restrict__ fc_w,
                                                      __hip_bfloat16* __restrict__ xout,
                                                      unsigned short* __restrict__ fcswz) {
    const int tid = threadIdx.x;
    const int bid = blockIdx.x;

    if (bid >= 2048) {
        const int base = (bid - 2048) * 2048 + tid * 8;
        const int l15 = (base >> 3) & 15;
        const int kg = (base >> 7) & 3;
        const int ks = (base >> 9) & 3;
        const int og = base >> 11;
        const int o = og * 16 + l15;
        short8 v;
        #pragma unroll
        for (int e = 0; e < 8; ++e) {
            const int w = ks * 32 + kg * 8 + e;
            v[e] = (short)((w < WIN) ? f2bf(fc_w[o * WIN + w]) : (unsigned short)0);
        }
        *(short8*)(fcswz + base) = v;
        return;
    }

    __shared__ int hist[2][NUM_BINS];
    __shared__ float red[2][4];

    hist[0][tid] = 0; hist[0][tid + 256] = 0;
    hist[1][tid] = 0; hist[1][tid + 256] = 0;
    __syncthreads();

    // frame 0: pixel-major interleave, int3 (12B) lane stride -> contiguous
    // 768B/wave per instruction, every fetched line fully consumed.
    const int* base0 = frames + (size_t)bid * 24576;
    #pragma unroll 8
    for (int i = 0; i < 16; ++i) {
        int3 v = *(const int3*)(base0 + (i * 256 + tid) * 3);
        atomicAdd(&hist[0][bin3(v)], 1);
    }
    __syncthreads();

    // frame 1 atomics start immediately; overlap frame-0 reduce/write below.
    const int* base1 = base0 + 12288;
    #pragma unroll 8
    for (int i = 0; i < 16; ++i) {
        int3 v = *(const int3*)(base1 + (i * 256 + tid) * 3);
        atomicAdd(&hist[1][bin3(v)], 1);
    }

    const int lane = tid & 63;
    const int wave = tid >> 6;

    const int a0 = hist[0][tid];
    const int a1 = hist[0][tid + 256];
    float ss0 = (float)a0 * (float)a0 + (float)a1 * (float)a1;
    #pragma unroll
    for (int off = 32; off; off >>= 1) ss0 += __shfl_down(ss0, off, 64);
    if (lane == 0) red[0][wave] = ss0;
    __syncthreads();   // red[0] ready; also fences all frame-1 atomics
    {
        const float inv = 1.0f / sqrtf(red[0][0] + red[0][1] + red[0][2] + red[0][3]);
        __hip_bfloat16* xrow = xout + (size_t)(bid * 2) * NUM_BINS;
        xrow[tid] = __float2bfloat16((float)a0 * inv);
        xrow[tid + 256] = __float2bfloat16((float)a1 * inv);
    }
    const int b0 = hist[1][tid];
    const int b1 = hist[1][tid + 256];
    float ss1 = (float)b0 * (float)b0 + (float)b1 * (float)b1;
    #pragma unroll
    for (int off = 32; off; off >>= 1) ss1 += __shfl_down(ss1, off, 64);
    if (lane == 0) red[1][wave] = ss1;
    __syncthreads();
    {
        const float inv = 1.0f / sqrtf(red[1][0] + red[1][1] + red[1][2] + red[1][3]);
        __hip_bfloat16* xrow = xout + (size_t)(bid * 2 + 1) * NUM_BINS;
        xrow[tid] = __float2bfloat16((float)b0 * inv);
        xrow[tid + 256] = __float2bfloat16((float)b1 * inv);
    }
}

// ---------------- Kernel 2: MFMA banded sim + window extract + MFMA FC -------
// grid = 256 blocks (XCD = b%8 keeps per-XCD x slice L2-hot), 512 threads.
// Phase 1: wave j computes s-tile j of the 16x128 sim band (16 MFMAs, K=512).
// Phase 2: diagonal extract win[i][w] = sim[i][i+w] -> bf16, zero-pad w>=101.
// Phase 3: wave j computes 16 FC outputs via pre-swizzled bf16 fc_w (4 MFMAs,
// coalesced short8 loads, no per-block f32->bf16 conversion).
__global__ __launch_bounds__(512) void simfc_kernel(const unsigned short* __restrict__ x,
                                                    const unsigned short* __restrict__ fcswz,
                                                    const float* __restrict__ fc_b,
                                                    float* __restrict__ out) {
    __shared__ float sim_lds[16 * 132];
    __shared__ unsigned short win_lds[16 * 136];

    const int bid = blockIdx.x;
    const int b = bid & 15;
    const int tt = bid >> 4;
    const int t0 = tt * 16;
    const int tid = threadIdx.x;
    const int lane = tid & 63;
    const int wave = tid >> 6;   // 0..7
    const int l15 = lane & 15;
    const int kg = lane >> 4;    // k-chunk 0..3

    const unsigned short* xb = x + (size_t)b * T_LEN * NUM_BINS;

    // ---- Phase 1: s-tile `wave`: cols s = t0-50+16*wave .. +15
    {
        f32x4 acc = {0.f, 0.f, 0.f, 0.f};
        const short8 zero8 = {0, 0, 0, 0, 0, 0, 0, 0};
        const int rowA = t0 + l15;
        const int rb = t0 - HALF + 16 * wave + l15;
        const bool vv = (rb >= 0) && (rb < T_LEN);
        const int rc = min(max(rb, 0), T_LEN - 1);
        const unsigned short* pa = xb + (size_t)rowA * NUM_BINS + kg * 8;
        const unsigned short* ps = xb + (size_t)rc * NUM_BINS + kg * 8;
        #pragma unroll
        for (int ks = 0; ks < 16; ++ks) {
            short8 a  = *(const short8*)(pa + ks * 32);
            short8 bb = *(const short8*)(ps + ks * 32);
            bb = vv ? bb : zero8;
            acc = __builtin_amdgcn_mfma_f32_16x16x32_bf16(a, bb, acc, 0, 0, 0);
        }
        #pragma unroll
        for (int r = 0; r < 4; ++r)
            sim_lds[(kg * 4 + r) * 132 + wave * 16 + l15] = acc[r];
    }
    __syncthreads();

    // ---- Phase 2: windowed[i][w] = sim[i][i+w], bf16, zero-pad w>=101.
    if (tid < 256) {
        const int i = tid >> 4;
        const int w8 = (tid & 15) * 8;
        short8 v;
        #pragma unroll
        for (int e = 0; e < 8; ++e) {
            const int w = w8 + e;
            const float fv = (w < WIN) ? sim_lds[i * 132 + i + w] : 0.0f;
            v[e] = (short)f2bf(fv);
        }
        *(short8*)(&win_lds[i * 136 + w8]) = v;
    }
    __syncthreads();

    // ---- Phase 3: wave owns outputs o = wave*16 + l15, K=128 MFMA.
    {
        f32x4 o0 = {0.f, 0.f, 0.f, 0.f};
        const int o = wave * 16 + l15;
        #pragma unroll
        for (int ks = 0; ks < 4; ++ks) {
            short8 a = *(const short8*)(&win_lds[l15 * 136 + ks * 32 + kg * 8]);
            short8 b0 = *(const short8*)(fcswz + ((((wave * 4 + ks) * 4 + kg) * 16 + l15) * 8));
            o0 = __builtin_amdgcn_mfma_f32_16x16x32_bf16(a, b0, o0, 0, 0, 0);
        }
        const float bias = fc_b[o];
        float* ob = out + ((size_t)b * T_LEN + t0) * NOUT;
        #pragma unroll
        for (int r = 0; r < 4; ++r)
            ob[(kg * 4 + r) * NOUT + o] = fmaxf(o0[r] + bias, 0.0f);
    }
}

extern "C" void kernel_launch(void* const* d_in, const int* in_sizes, int n_in,
                              void* d_out, int out_size, void* d_ws, size_t ws_size,
                              hipStream_t stream) {
    const int* frames = (const int*)d_in[0];
    const float* fc_w = (const float*)d_in[1];
    const float* fc_b = (const float*)d_in[2];
    float* out = (float*)d_out;
    __hip_bfloat16* x = (__hip_bfloat16*)d_ws;                       // 4 MB
    unsigned short* fcswz = (unsigned short*)((char*)d_ws + (4 << 20)); // 32 KB

    hist_kernel<<<2048 + 8, 256, 0, stream>>>(frames, fc_w, x, fcswz);
    simfc_kernel<<<256, 512, 0, stream>>>((const unsigned short*)x, fcswz, fc_b, out);
}

// Round 7
// 44.033 us; speedup vs baseline: 2.2683x; 1.0092x over previous
//
#include <hip/hip_runtime.h>
#include <hip/hip_bf16.h>

#define NUM_BINS 512
#define T_LEN 256
#define B_LEN 16
#define WIN 101
#define HALF 50
#define NOUT 128

typedef __attribute__((ext_vector_type(8))) short short8;
typedef __attribute__((ext_vector_type(4))) float f32x4;

__device__ __forceinline__ unsigned short f2bf(float f) {
    unsigned u = __float_as_uint(f);
    u += 0x7fff + ((u >> 16) & 1);   // round-to-nearest-even
    return (unsigned short)(u >> 16);
}

// ---------------- Kernel 1: histograms (2 frames/block) + fc_w preswizzle ----
// 2048 frame-blocks (2 frames each) + 8 tail blocks converting fc_w to the
// bf16 MFMA B-fragment layout [og][ks][kg][l15][e], zero-padded to K=128.
// Load pattern: pixel-quad ownership — thread t, iter i loads 3 consecutive
// int4 (48 B = exactly 4 pixels) at 48 B lane stride; each dwordx4 spans a
// contiguous 3 KB/wave and the back-to-back trio fully consumes every line.
__global__ __launch_bounds__(256, 6) void hist_kernel(const int* __restrict__ frames,
                                                      const float* __restrict__ fc_w,
                                                      __hip_bfloat16* __restrict__ xout,
                                                      unsigned short* __restrict__ fcswz) {
    const int tid = threadIdx.x;
    const int bid = blockIdx.x;

    if (bid >= 2048) {
        const int base = (bid - 2048) * 2048 + tid * 8;
        const int l15 = (base >> 3) & 15;
        const int kg = (base >> 7) & 3;
        const int ks = (base >> 9) & 3;
        const int og = base >> 11;
        const int o = og * 16 + l15;
        short8 v;
        #pragma unroll
        for (int e = 0; e < 8; ++e) {
            const int w = ks * 32 + kg * 8 + e;
            v[e] = (short)((w < WIN) ? f2bf(fc_w[o * WIN + w]) : (unsigned short)0);
        }
        *(short8*)(fcswz + base) = v;
        return;
    }

    __shared__ int hist[2][NUM_BINS];
    __shared__ float red[2][4];

    hist[0][tid] = 0; hist[0][tid + 256] = 0;
    hist[1][tid] = 0; hist[1][tid + 256] = 0;
    __syncthreads();

    const int4* f4 = (const int4*)(frames + (size_t)bid * 24576);

    // frame 0 (int4 indices 0..3071)
    #pragma unroll
    for (int i = 0; i < 4; ++i) {
        const int q = (i * 256 + tid) * 3;
        int4 a = f4[q + 0];
        int4 b = f4[q + 1];
        int4 c = f4[q + 2];
        atomicAdd(&hist[0][((a.x >> 5) << 6) | ((a.y >> 5) << 3) | (a.z >> 5)], 1);
        atomicAdd(&hist[0][((a.w >> 5) << 6) | ((b.x >> 5) << 3) | (b.y >> 5)], 1);
        atomicAdd(&hist[0][((b.z >> 5) << 6) | ((b.w >> 5) << 3) | (c.x >> 5)], 1);
        atomicAdd(&hist[0][((c.y >> 5) << 6) | ((c.z >> 5) << 3) | (c.w >> 5)], 1);
    }
    __syncthreads();

    // frame 1 (int4 indices 3072..6143); atomics overlap frame-0 reduce below.
    #pragma unroll
    for (int i = 0; i < 4; ++i) {
        const int q = 3072 + (i * 256 + tid) * 3;
        int4 a = f4[q + 0];
        int4 b = f4[q + 1];
        int4 c = f4[q + 2];
        atomicAdd(&hist[1][((a.x >> 5) << 6) | ((a.y >> 5) << 3) | (a.z >> 5)], 1);
        atomicAdd(&hist[1][((a.w >> 5) << 6) | ((b.x >> 5) << 3) | (b.y >> 5)], 1);
        atomicAdd(&hist[1][((b.z >> 5) << 6) | ((b.w >> 5) << 3) | (c.x >> 5)], 1);
        atomicAdd(&hist[1][((c.y >> 5) << 6) | ((c.z >> 5) << 3) | (c.w >> 5)], 1);
    }

    const int lane = tid & 63;
    const int wave = tid >> 6;

    const int a0 = hist[0][tid];
    const int a1 = hist[0][tid + 256];
    float ss0 = (float)a0 * (float)a0 + (float)a1 * (float)a1;
    #pragma unroll
    for (int off = 32; off; off >>= 1) ss0 += __shfl_down(ss0, off, 64);
    if (lane == 0) red[0][wave] = ss0;
    __syncthreads();   // red[0] ready; also fences all frame-1 atomics
    {
        const float inv = 1.0f / sqrtf(red[0][0] + red[0][1] + red[0][2] + red[0][3]);
        __hip_bfloat16* xrow = xout + (size_t)(bid * 2) * NUM_BINS;
        xrow[tid] = __float2bfloat16((float)a0 * inv);
        xrow[tid + 256] = __float2bfloat16((float)a1 * inv);
    }
    const int b0 = hist[1][tid];
    const int b1 = hist[1][tid + 256];
    float ss1 = (float)b0 * (float)b0 + (float)b1 * (float)b1;
    #pragma unroll
    for (int off = 32; off; off >>= 1) ss1 += __shfl_down(ss1, off, 64);
    if (lane == 0) red[1][wave] = ss1;
    __syncthreads();
    {
        const float inv = 1.0f / sqrtf(red[1][0] + red[1][1] + red[1][2] + red[1][3]);
        __hip_bfloat16* xrow = xout + (size_t)(bid * 2 + 1) * NUM_BINS;
        xrow[tid] = __float2bfloat16((float)b0 * inv);
        xrow[tid + 256] = __float2bfloat16((float)b1 * inv);
    }
}

// ---------------- Kernel 2: MFMA banded sim + window extract + MFMA FC -------
// grid = 256 blocks (XCD = b%8 keeps per-XCD x slice L2-hot), 512 threads.
// Phase 1: wave j computes s-tile j of the 16x128 sim band (16 MFMAs, K=512).
// Phase 2: diagonal extract win[i][w] = sim[i][i+w] -> bf16, zero-pad w>=101.
// Phase 3: wave j computes 16 FC outputs via pre-swizzled bf16 fc_w (4 MFMAs).
__global__ __launch_bounds__(512) void simfc_kernel(const unsigned short* __restrict__ x,
                                                    const unsigned short* __restrict__ fcswz,
                                                    const float* __restrict__ fc_b,
                                                    float* __restrict__ out) {
    __shared__ float sim_lds[16 * 132];
    __shared__ unsigned short win_lds[16 * 136];

    const int bid = blockIdx.x;
    const int b = bid & 15;
    const int tt = bid >> 4;
    const int t0 = tt * 16;
    const int tid = threadIdx.x;
    const int lane = tid & 63;
    const int wave = tid >> 6;   // 0..7
    const int l15 = lane & 15;
    const int kg = lane >> 4;    // k-chunk 0..3

    const unsigned short* xb = x + (size_t)b * T_LEN * NUM_BINS;

    // ---- Phase 1: s-tile `wave`: cols s = t0-50+16*wave .. +15
    {
        f32x4 acc = {0.f, 0.f, 0.f, 0.f};
        const short8 zero8 = {0, 0, 0, 0, 0, 0, 0, 0};
        const int rowA = t0 + l15;
        const int rb = t0 - HALF + 16 * wave + l15;
        const bool vv = (rb >= 0) && (rb < T_LEN);
        const int rc = min(max(rb, 0), T_LEN - 1);
        const unsigned short* pa = xb + (size_t)rowA * NUM_BINS + kg * 8;
        const unsigned short* ps = xb + (size_t)rc * NUM_BINS + kg * 8;
        #pragma unroll
        for (int ks = 0; ks < 16; ++ks) {
            short8 a  = *(const short8*)(pa + ks * 32);
            short8 bb = *(const short8*)(ps + ks * 32);
            bb = vv ? bb : zero8;
            acc = __builtin_amdgcn_mfma_f32_16x16x32_bf16(a, bb, acc, 0, 0, 0);
        }
        #pragma unroll
        for (int r = 0; r < 4; ++r)
            sim_lds[(kg * 4 + r) * 132 + wave * 16 + l15] = acc[r];
    }
    __syncthreads();

    // ---- Phase 2: windowed[i][w] = sim[i][i+w], bf16, zero-pad w>=101.
    if (tid < 256) {
        const int i = tid >> 4;
        const int w8 = (tid & 15) * 8;
        short8 v;
        #pragma unroll
        for (int e = 0; e < 8; ++e) {
            const int w = w8 + e;
            const float fv = (w < WIN) ? sim_lds[i * 132 + i + w] : 0.0f;
            v[e] = (short)f2bf(fv);
        }
        *(short8*)(&win_lds[i * 136 + w8]) = v;
    }
    __syncthreads();

    // ---- Phase 3: wave owns outputs o = wave*16 + l15, K=128 MFMA.
    {
        f32x4 o0 = {0.f, 0.f, 0.f, 0.f};
        const int o = wave * 16 + l15;
        #pragma unroll
        for (int ks = 0; ks < 4; ++ks) {
            short8 a = *(const short8*)(&win_lds[l15 * 136 + ks * 32 + kg * 8]);
            short8 b0 = *(const short8*)(fcswz + ((((wave * 4 + ks) * 4 + kg) * 16 + l15) * 8));
            o0 = __builtin_amdgcn_mfma_f32_16x16x32_bf16(a, b0, o0, 0, 0, 0);
        }
        const float bias = fc_b[o];
        float* ob = out + ((size_t)b * T_LEN + t0) * NOUT;
        #pragma unroll
        for (int r = 0; r < 4; ++r)
            ob[(kg * 4 + r) * NOUT + o] = fmaxf(o0[r] + bias, 0.0f);
    }
}

extern "C" void kernel_launch(void* const* d_in, const int* in_sizes, int n_in,
                              void* d_out, int out_size, void* d_ws, size_t ws_size,
                              hipStream_t stream) {
    const int* frames = (const int*)d_in[0];
    const float* fc_w = (const float*)d_in[1];
    const float* fc_b = (const float*)d_in[2];
    float* out = (float*)d_out;
    __hip_bfloat16* x = (__hip_bfloat16*)d_ws;                          // 4 MB
    unsigned short* fcswz = (unsigned short*)((char*)d_ws + (4 << 20)); // 32 KB

    hist_kernel<<<2048 + 8, 256, 0, stream>>>(frames, fc_w, x, fcswz);
    simfc_kernel<<<256, 512, 0, stream>>>((const unsigned short*)x, fcswz, fc_b, out);
}